// Round 9
// baseline (211.958 us; speedup 1.0000x reference)
//
#include <hip/hip_runtime.h>
#include <math.h>

#define N 16384
#define F 256
#define K_KEEP 8192
#define QS 4096    // columns per apool block (quarter row)
#define APOOL_BLOCKS (K_KEEP * 4)

typedef float f32x4 __attribute__((ext_vector_type(4)));  // native vec for nontemporal builtins

// ---------------------------------------------------------------------------
// Kernel 1: y[i] = dot(X[i,:], p)/||p|| (fp64 accum) + monotone u64 sort key.
// One wave per row; lane l covers 4 consecutive floats.
// ---------------------------------------------------------------------------
__global__ __launch_bounds__(256) void score_kernel(const float* __restrict__ X,
                                                    const float* __restrict__ p,
                                                    double* __restrict__ y,
                                                    unsigned long long* __restrict__ key) {
    const int wave = threadIdx.x >> 6;
    const int lane = threadIdx.x & 63;
    const int row  = blockIdx.x * 4 + wave;

    const float4 pv = *reinterpret_cast<const float4*>(p + lane * 4);
    const float4 xv = *reinterpret_cast<const float4*>(X + (size_t)row * F + lane * 4);

    double pp = (double)pv.x * pv.x + (double)pv.y * pv.y +
                (double)pv.z * pv.z + (double)pv.w * pv.w;
    double xp = (double)xv.x * pv.x + (double)xv.y * pv.y +
                (double)xv.z * pv.z + (double)xv.w * pv.w;

    #pragma unroll
    for (int off = 32; off >= 1; off >>= 1) {
        pp += __shfl_down(pp, off, 64);
        xp += __shfl_down(xp, off, 64);
    }
    if (lane == 0) {
        const double yy = xp / sqrt(pp);
        y[row] = yy;
        const long long b = __double_as_longlong(yy);
        key[row] = (unsigned long long)b ^
                   ((b < 0) ? 0xFFFFFFFFFFFFFFFFULL : 0x8000000000000000ULL);
    }
}

// ---------------------------------------------------------------------------
// Kernel 2 (single block): radix-select the K-th largest key (0-based rank
// K_KEEP-1 descending). 3 levels x 12 bits (4096-bucket LDS histogram +
// parallel suffix scan), then exact count-select among prefix-matching
// candidates. Keys are distinct doubles.
// ---------------------------------------------------------------------------
__global__ __launch_bounds__(256) void select_kernel(const unsigned long long* __restrict__ key,
                                                     unsigned long long* __restrict__ thr_out) {
    __shared__ int hist[4096];
    __shared__ int part[256];
    __shared__ int bres[2];
    __shared__ unsigned long long cand[256];
    __shared__ int ccnt;
    const int t = threadIdx.x;

    int rank = K_KEEP - 1;                 // 0-based descending rank
    unsigned long long pval = 0, pmask = 0;

    for (int lvl = 0; lvl < 3; ++lvl) {
        const int shift = 52 - lvl * 12;
        #pragma unroll
        for (int q = 0; q < 16; ++q) hist[q * 256 + t] = 0;
        __syncthreads();

        for (int i = t; i < N; i += 256) {
            const unsigned long long k = key[i];
            if ((k & pmask) == pval)
                atomicAdd(&hist[(int)((k >> shift) & 0xFFF)], 1);
        }
        __syncthreads();

        int ps = 0;
        #pragma unroll
        for (int q = 0; q < 16; ++q) ps += hist[t * 16 + q];
        part[t] = ps;
        __syncthreads();
        for (int off = 1; off < 256; off <<= 1) {
            const int v = (t >= off) ? part[t - off] : 0;
            __syncthreads();
            part[t] += v;
            __syncthreads();
        }
        const int total = part[255];
        int acc = total - part[t];         // keys in buckets above this thread's range
        int fb = -1, fr = 0;
        #pragma unroll
        for (int q = 15; q >= 0; --q) {
            const int b = t * 16 + q;
            const int h = hist[b];
            if (fb < 0 && acc <= rank && acc + h > rank) { fb = b; fr = rank - acc; }
            acc += h;
        }
        if (fb >= 0) { bres[0] = fb; bres[1] = fr; }
        __syncthreads();
        const int b = bres[0];
        rank = bres[1];
        pval |= ((unsigned long long)b) << shift;
        pmask |= (0xFFFULL << shift);
        __syncthreads();
    }

    if (t == 0) ccnt = 0;
    __syncthreads();
    for (int i = t; i < N; i += 256) {
        const unsigned long long k = key[i];
        if ((k & pmask) == pval) {
            const int pos = atomicAdd(&ccnt, 1);
            if (pos < 256) cand[pos] = k;
        }
    }
    __syncthreads();
    const int c = (ccnt < 256) ? ccnt : 256;
    if (t < c) {
        const unsigned long long kk = cand[t];
        int cnt = 0;
        for (int j = 0; j < c; ++j) cnt += (int)(cand[j] > kk);
        if (cnt == rank) *thr_out = kk;
    }
}

// ---------------------------------------------------------------------------
// Kernel 3: kept flags = (key >= thr), ballot into 64-bit words.
// ---------------------------------------------------------------------------
__global__ __launch_bounds__(256) void flags_kernel(const unsigned long long* __restrict__ key,
                                                    const unsigned long long* __restrict__ thr,
                                                    unsigned long long* __restrict__ flagbits) {
    const int i = blockIdx.x * 256 + threadIdx.x;
    const bool kept = key[i] >= *thr;
    const unsigned long long m = __ballot(kept);
    if ((threadIdx.x & 63) == 0) flagbits[i >> 6] = m;
}

// ---------------------------------------------------------------------------
// Kernel 4 (single block): popcount+scan the 256 flag words -> wexcl[256];
// emit ascending kept indices idx[] and in-quarter u16 source offsets srcq[].
// ---------------------------------------------------------------------------
__global__ __launch_bounds__(256) void emit_kernel(const unsigned long long* __restrict__ flagbits,
                                                   int* __restrict__ idx,
                                                   unsigned short* __restrict__ srcq,
                                                   int* __restrict__ wexcl) {
    __shared__ int sc[256];
    const int t = threadIdx.x;
    const unsigned long long m = flagbits[t];
    const int c = __popcll(m);
    sc[t] = c;
    __syncthreads();
    for (int off = 1; off < 256; off <<= 1) {
        const int v = (t >= off) ? sc[t - off] : 0;
        __syncthreads();
        sc[t] += v;
        __syncthreads();
    }
    const int excl = sc[t] - c;
    wexcl[t] = excl;

    int base = excl;
    unsigned long long mm = m;
    const int col = t * 64;
    while (mm) {
        const int b = __ffsll((long long)mm) - 1;
        mm &= (mm - 1);
        const int i = col + b;
        idx[base]  = i;
        srcq[base] = (unsigned short)(i & (QS - 1));
        ++base;
    }
}

// ---------------------------------------------------------------------------
// Kernel 5 (fused pool): blocks [0, 32768): A_pooled via LDS-staged quarter
// row + srcq gather + aligned float4 nontemporal stores. Blocks [32768, +2048):
// X_pooled (one wave per kept row).
// ---------------------------------------------------------------------------
__global__ __launch_bounds__(256) void pool_kernel(const float* __restrict__ A,
                                                   const float* __restrict__ X,
                                                   const double* __restrict__ y,
                                                   const int* __restrict__ idx,
                                                   const unsigned short* __restrict__ srcq,
                                                   const int* __restrict__ wexcl,
                                                   float* __restrict__ outX,
                                                   float* __restrict__ outA) {
    const int t = threadIdx.x;

    if (blockIdx.x >= APOOL_BLOCKS) {  // ---- xpool part ----
        const int k    = (blockIdx.x - APOOL_BLOCKS) * 4 + (t >> 6);
        const int lane = t & 63;
        const int src  = idx[k];
        const float tf = tanhf((float)y[src]);
        const float4 xv = *reinterpret_cast<const float4*>(X + (size_t)src * F + lane * 4);
        float4 o = {xv.x * tf, xv.y * tf, xv.z * tf, xv.w * tf};
        *reinterpret_cast<float4*>(outX + (size_t)k * F + lane * 4) = o;
        return;
    }

    // ---- apool part: one (row, quarter) per block ----
    __shared__ float buf[QS];
    const int row  = blockIdx.x >> 2;
    const int h    = blockIdx.x & 3;
    const int ridx = idx[row];                    // uniform
    const int kb   = wexcl[h * 64];               // uniform
    const int ke   = (h < 3) ? wexcl[h * 64 + 64] : K_KEEP;

    const f32x4* __restrict__ a4 =
        reinterpret_cast<const f32x4*>(A + (size_t)ridx * N + h * QS);
    f32x4* __restrict__ b4 = reinterpret_cast<f32x4*>(buf);
    #pragma unroll
    for (int s = 0; s < 4; ++s) b4[s * 256 + t] = __builtin_nontemporal_load(a4 + s * 256 + t);
    __syncthreads();

    float* __restrict__ orow = outA + (size_t)row * K_KEEP;
    const int k4b = (kb + 3) & ~3;
    const int k4e = ke & ~3;
    if (t < (k4b - kb)) orow[kb + t] = buf[srcq[kb + t]];
    if (t < (ke - k4e)) orow[k4e + t] = buf[srcq[k4e + t]];
    for (int k4 = k4b + 4 * t; k4 < k4e; k4 += 1024) {
        const ushort4 s4 = *reinterpret_cast<const ushort4*>(srcq + k4);
        f32x4 v = {buf[s4.x], buf[s4.y], buf[s4.z], buf[s4.w]};
        __builtin_nontemporal_store(v, reinterpret_cast<f32x4*>(orow + k4));
    }
}

// ---------------------------------------------------------------------------
extern "C" void kernel_launch(void* const* d_in, const int* in_sizes, int n_in,
                              void* d_out, int out_size, void* d_ws, size_t ws_size,
                              hipStream_t stream) {
    const float* X = (const float*)d_in[0];  // [N, F]
    const float* A = (const float*)d_in[1];  // [N, N]
    const float* p = (const float*)d_in[2];  // [F, 1]

    float* out  = (float*)d_out;
    float* outX = out;                          // [K_KEEP, F]
    float* outA = out + (size_t)K_KEEP * F;     // [K_KEEP, K_KEEP]

    char* ws = (char*)d_ws;
    double*             y        = (double*)ws;                           // 131072 B
    unsigned long long* key      = (unsigned long long*)(ws + 131072);    // 131072 B
    unsigned long long* flagbits = (unsigned long long*)(ws + 262144);    // 2048 B
    int*                wexcl    = (int*)(ws + 264192);                   // 1024 B
    int*                idx      = (int*)(ws + 265216);                   // 32768 B
    unsigned short*     srcq     = (unsigned short*)(ws + 297984);        // 16384 B
    unsigned long long* thr      = (unsigned long long*)(ws + 314368);    // 8 B

    score_kernel<<<N / 4, 256, 0, stream>>>(X, p, y, key);
    select_kernel<<<1, 256, 0, stream>>>(key, thr);
    flags_kernel<<<N / 256, 256, 0, stream>>>(key, thr, flagbits);
    emit_kernel<<<1, 256, 0, stream>>>(flagbits, idx, srcq, wexcl);
    pool_kernel<<<APOOL_BLOCKS + K_KEEP / 4, 256, 0, stream>>>(A, X, y, idx, srcq, wexcl,
                                                               outX, outA);
}

// Round 10
// 175.875 us; speedup vs baseline: 1.2052x; 1.2052x over previous
//
#include <hip/hip_runtime.h>
#include <math.h>

#define N 16384
#define F 256
#define K_KEEP 8192
#define JCH 512    // keys per j-chunk in rank kernel
#define IPT 4      // i per thread in rank kernel
#define NCH (N / JCH)  // 32 j-chunks
#define QS 4096    // columns per apool block (quarter row)
#define APOOL_BLOCKS (K_KEEP * 4)

typedef float f32x4 __attribute__((ext_vector_type(4)));  // native vec for nontemporal builtins

// ---------------------------------------------------------------------------
// Kernel 1: y[i] = dot(X[i,:], p)/||p|| (fp64 accum); store f32 y + monotone
// u32 sort key of (float)y. Near the K-boundary (median ~ 0) adjacent order
// stats differ by ~1.5e-4 while f32 spacing there is ~1e-12, so u32-key
// ranking equals f64 ranking. One wave per row.
// ---------------------------------------------------------------------------
__global__ __launch_bounds__(256) void score_kernel(const float* __restrict__ X,
                                                    const float* __restrict__ p,
                                                    float* __restrict__ y,
                                                    unsigned int* __restrict__ key) {
    const int wave = threadIdx.x >> 6;
    const int lane = threadIdx.x & 63;
    const int row  = blockIdx.x * 4 + wave;

    const float4 pv = *reinterpret_cast<const float4*>(p + lane * 4);
    const float4 xv = *reinterpret_cast<const float4*>(X + (size_t)row * F + lane * 4);

    double pp = (double)pv.x * pv.x + (double)pv.y * pv.y +
                (double)pv.z * pv.z + (double)pv.w * pv.w;
    double xp = (double)xv.x * pv.x + (double)xv.y * pv.y +
                (double)xv.z * pv.z + (double)xv.w * pv.w;

    #pragma unroll
    for (int off = 32; off >= 1; off >>= 1) {
        pp += __shfl_down(pp, off, 64);
        xp += __shfl_down(xp, off, 64);
    }
    if (lane == 0) {
        const float yf = (float)(xp / sqrt(pp));
        y[row] = yf;
        const unsigned int b = __float_as_uint(yf);
        key[row] = b ^ (((int)b < 0) ? 0xFFFFFFFFu : 0x80000000u);
    }
}

// ---------------------------------------------------------------------------
// Kernel 2: partial ranks via u32 keys. IPT=4 i per thread; each ds_read_b128
// fetches 4 keys -> 16 compares per LDS instruction. Strict > (keys distinct
// at the boundary per the f32-spacing argument).
// ---------------------------------------------------------------------------
__global__ __launch_bounds__(256) void rank_kernel(const unsigned int* __restrict__ key,
                                                   unsigned short* __restrict__ rankp) {
    __shared__ uint4 kch4[JCH / 4];   // 2 KB
    const int t     = threadIdx.x;
    const int jc    = blockIdx.y;
    const int jbase = jc * JCH;
    if (t < JCH / 4) kch4[t] = reinterpret_cast<const uint4*>(key + jbase)[t];
    __syncthreads();

    const int ibase = blockIdx.x * (256 * IPT) + t;
    const unsigned int k0 = key[ibase];
    const unsigned int k1 = key[ibase + 256];
    const unsigned int k2 = key[ibase + 512];
    const unsigned int k3 = key[ibase + 768];
    int c0 = 0, c1 = 0, c2 = 0, c3 = 0;
    #pragma unroll 8
    for (int jj = 0; jj < JCH / 4; ++jj) {
        const uint4 kk = kch4[jj];
        c0 += (int)(kk.x > k0) + (int)(kk.y > k0) + (int)(kk.z > k0) + (int)(kk.w > k0);
        c1 += (int)(kk.x > k1) + (int)(kk.y > k1) + (int)(kk.z > k1) + (int)(kk.w > k1);
        c2 += (int)(kk.x > k2) + (int)(kk.y > k2) + (int)(kk.z > k2) + (int)(kk.w > k2);
        c3 += (int)(kk.x > k3) + (int)(kk.y > k3) + (int)(kk.z > k3) + (int)(kk.w > k3);
    }
    rankp[jc * N + ibase      ] = (unsigned short)c0;
    rankp[jc * N + ibase + 256] = (unsigned short)c1;
    rankp[jc * N + ibase + 512] = (unsigned short)c2;
    rankp[jc * N + ibase + 768] = (unsigned short)c3;
}

// ---------------------------------------------------------------------------
// Kernel 3: total rank -> kept flags (64-bit words).
// ---------------------------------------------------------------------------
__global__ __launch_bounds__(256) void flags_kernel(const unsigned short* __restrict__ rankp,
                                                    unsigned long long* __restrict__ flagbits) {
    const int i = blockIdx.x * 256 + threadIdx.x; // coalesced
    int r = 0;
    #pragma unroll
    for (int jc = 0; jc < NCH; ++jc) r += (int)rankp[jc * N + i];
    const bool kept = (r < K_KEEP);
    const unsigned long long m = __ballot(kept);
    if ((threadIdx.x & 63) == 0) flagbits[i >> 6] = m;
}

// ---------------------------------------------------------------------------
// Kernel 4 (single block): popcount+scan the 256 flag words -> wexcl[256];
// emit ascending kept indices idx[] and in-quarter u16 source offsets srcq[].
// ---------------------------------------------------------------------------
__global__ __launch_bounds__(256) void emit_kernel(const unsigned long long* __restrict__ flagbits,
                                                   int* __restrict__ idx,
                                                   unsigned short* __restrict__ srcq,
                                                   int* __restrict__ wexcl) {
    __shared__ int sc[256];
    const int t = threadIdx.x;
    const unsigned long long m = flagbits[t];
    const int c = __popcll(m);
    sc[t] = c;
    __syncthreads();
    for (int off = 1; off < 256; off <<= 1) {
        const int v = (t >= off) ? sc[t - off] : 0;
        __syncthreads();
        sc[t] += v;
        __syncthreads();
    }
    const int excl = sc[t] - c;
    wexcl[t] = excl;

    int base = excl;
    unsigned long long mm = m;
    const int col = t * 64;
    while (mm) {
        const int b = __ffsll((long long)mm) - 1;
        mm &= (mm - 1);
        const int i = col + b;
        idx[base]  = i;
        srcq[base] = (unsigned short)(i & (QS - 1));
        ++base;
    }
}

// ---------------------------------------------------------------------------
// Kernel 5 (fused pool): blocks [0, 32768): A_pooled via LDS-staged quarter
// row + srcq gather + aligned float4 nontemporal stores. Blocks [32768, +2048):
// X_pooled (one wave per kept row).
// ---------------------------------------------------------------------------
__global__ __launch_bounds__(256) void pool_kernel(const float* __restrict__ A,
                                                   const float* __restrict__ X,
                                                   const float* __restrict__ y,
                                                   const int* __restrict__ idx,
                                                   const unsigned short* __restrict__ srcq,
                                                   const int* __restrict__ wexcl,
                                                   float* __restrict__ outX,
                                                   float* __restrict__ outA) {
    const int t = threadIdx.x;

    if (blockIdx.x >= APOOL_BLOCKS) {  // ---- xpool part ----
        const int k    = (blockIdx.x - APOOL_BLOCKS) * 4 + (t >> 6);
        const int lane = t & 63;
        const int src  = idx[k];
        const float tf = tanhf(y[src]);
        const float4 xv = *reinterpret_cast<const float4*>(X + (size_t)src * F + lane * 4);
        float4 o = {xv.x * tf, xv.y * tf, xv.z * tf, xv.w * tf};
        *reinterpret_cast<float4*>(outX + (size_t)k * F + lane * 4) = o;
        return;
    }

    // ---- apool part: one (row, quarter) per block ----
    __shared__ float buf[QS];
    const int row  = blockIdx.x >> 2;
    const int h    = blockIdx.x & 3;
    const int ridx = idx[row];                    // uniform
    const int kb   = wexcl[h * 64];               // uniform
    const int ke   = (h < 3) ? wexcl[h * 64 + 64] : K_KEEP;

    const f32x4* __restrict__ a4 =
        reinterpret_cast<const f32x4*>(A + (size_t)ridx * N + h * QS);
    f32x4* __restrict__ b4 = reinterpret_cast<f32x4*>(buf);
    #pragma unroll
    for (int s = 0; s < 4; ++s) b4[s * 256 + t] = __builtin_nontemporal_load(a4 + s * 256 + t);
    __syncthreads();

    float* __restrict__ orow = outA + (size_t)row * K_KEEP;
    const int k4b = (kb + 3) & ~3;
    const int k4e = ke & ~3;
    if (t < (k4b - kb)) orow[kb + t] = buf[srcq[kb + t]];
    if (t < (ke - k4e)) orow[k4e + t] = buf[srcq[k4e + t]];
    for (int k4 = k4b + 4 * t; k4 < k4e; k4 += 1024) {
        const ushort4 s4 = *reinterpret_cast<const ushort4*>(srcq + k4);
        f32x4 v = {buf[s4.x], buf[s4.y], buf[s4.z], buf[s4.w]};
        __builtin_nontemporal_store(v, reinterpret_cast<f32x4*>(orow + k4));
    }
}

// ---------------------------------------------------------------------------
extern "C" void kernel_launch(void* const* d_in, const int* in_sizes, int n_in,
                              void* d_out, int out_size, void* d_ws, size_t ws_size,
                              hipStream_t stream) {
    const float* X = (const float*)d_in[0];  // [N, F]
    const float* A = (const float*)d_in[1];  // [N, N]
    const float* p = (const float*)d_in[2];  // [F, 1]

    float* out  = (float*)d_out;
    float* outX = out;                          // [K_KEEP, F]
    float* outA = out + (size_t)K_KEEP * F;     // [K_KEEP, K_KEEP]

    char* ws = (char*)d_ws;
    float*              y        = (float*)ws;                            // 65536 B
    unsigned int*       key      = (unsigned int*)(ws + 65536);           // 65536 B
    unsigned short*     rankp    = (unsigned short*)(ws + 131072);        // 32*N*2 = 1048576 B
    unsigned long long* flagbits = (unsigned long long*)(ws + 1179648);   // 2048 B
    int*                wexcl    = (int*)(ws + 1181696);                  // 1024 B
    int*                idx      = (int*)(ws + 1182720);                  // 32768 B
    unsigned short*     srcq     = (unsigned short*)(ws + 1215488);       // 16384 B

    score_kernel<<<N / 4, 256, 0, stream>>>(X, p, y, key);
    rank_kernel<<<dim3(N / (256 * IPT), NCH), 256, 0, stream>>>(key, rankp);
    flags_kernel<<<N / 256, 256, 0, stream>>>(rankp, flagbits);
    emit_kernel<<<1, 256, 0, stream>>>(flagbits, idx, srcq, wexcl);
    pool_kernel<<<APOOL_BLOCKS + K_KEEP / 4, 256, 0, stream>>>(A, X, y, idx, srcq, wexcl,
                                                               outX, outA);
}